// Round 1
// baseline (45967.590 us; speedup 1.0000x reference)
//
#include <hip/hip_runtime.h>

#define SCOPE_AGENT __HIP_MEMORY_SCOPE_AGENT

using short8 = __attribute__((ext_vector_type(8))) short;
using f32x4  = __attribute__((ext_vector_type(4))) float;

static constexpr int TT   = 2048;   // time steps
static constexpr int NB   = 16;     // batch
static constexpr int SS   = 512;    // state dim
static constexpr int NCH  = 32;     // column chunks of 16
static constexpr int MROWS = NB * TT; // 32768 GEMM rows

__device__ __forceinline__ unsigned short f2bf(float f) {
    unsigned u = __builtin_bit_cast(unsigned, f);
    u += 0x7FFFu + ((u >> 16) & 1u);
    return (unsigned short)(u >> 16);
}
__device__ __forceinline__ float bf2f(unsigned short h) {
    return __builtin_bit_cast(float, ((unsigned)h) << 16);
}

// -------------------- zero init (flags/stats) --------------------
__global__ void zero_kernel(unsigned int* __restrict__ p, int n) {
    int i = blockIdx.x * blockDim.x + threadIdx.x;
    int stride = gridDim.x * blockDim.x;
    for (; i < n; i += stride) p[i] = 0u;
}

// -------------------- transpose + fp32->bf16 (512x512) --------------------
// out[c][r] = in[r][c]
__global__ __launch_bounds__(256) void tcvt_kernel(const float* __restrict__ in,
                                                   unsigned short* __restrict__ out) {
    __shared__ float tile[32][33];
    int bid = blockIdx.x;
    int rb = (bid >> 4) * 32, cb = (bid & 15) * 32;
    int tx = threadIdx.x & 31, ty = threadIdx.x >> 5;
    for (int rr = ty; rr < 32; rr += 8)
        tile[rr][tx] = in[(size_t)(rb + rr) * SS + cb + tx];
    __syncthreads();
    for (int rr = ty; rr < 32; rr += 8)
        out[(size_t)(cb + rr) * SS + rb + tx] = f2bf(tile[tx][rr]);
}

// -------------------- W = C0 @ B1 (512x512x512 fp32) --------------------
__global__ __launch_bounds__(256) void wmm_kernel(const float* __restrict__ C0,
                                                  const float* __restrict__ B1,
                                                  float* __restrict__ W) {
    int k = blockIdx.x;           // output row
    int tid = threadIdx.x;
    const float* crow = C0 + (size_t)k * SS;
    float s0 = 0.f, s1 = 0.f;
    for (int m = 0; m < SS; ++m) {
        float cv = crow[m];
        s0 += cv * B1[(size_t)m * SS + tid];
        s1 += cv * B1[(size_t)m * SS + tid + 256];
    }
    W[(size_t)k * SS + tid] = s0;
    W[(size_t)k * SS + tid + 256] = s1;
}

// -------------------- big GEMM: Out = Arows @ B^T-frags --------------------
// M=32768, N=512, K=512. BT is [n][k] bf16.
// AFP32: A is fp32 [r][k] (x input) else bf16 [r][k] (hs).
// MODE 0: write U bf16 in scan layout [t][g][b][c]; MODE 1: write fp32 out[r][n].
template <bool AFP32, int MODE>
__global__ __launch_bounds__(256) void gemm_kernel(const void* __restrict__ Aptr,
                                                   const unsigned short* __restrict__ BT,
                                                   void* __restrict__ Outp) {
    int lane = threadIdx.x & 63;
    int wv   = threadIdx.x >> 6;
    int wid  = blockIdx.x * 4 + wv;          // 16384 wave-tiles
    int mt   = wid >> 3;                     // 2048 m-tiles of 16 rows
    int nb   = (wid & 7) * 64;               // 8 n-tiles of 64 cols
    int mbase = mt * 16;
    int lo = lane & 15, q = lane >> 4;

    f32x4 acc[4] = {{0,0,0,0},{0,0,0,0},{0,0,0,0},{0,0,0,0}};

    const float* Af = (const float*)Aptr;
    const unsigned short* Ab = (const unsigned short*)Aptr;

    #pragma unroll 2
    for (int kk = 0; kk < 16; ++kk) {
        int koff = kk * 32 + q * 8;
        short8 af;
        if (AFP32) {
            const float* ar = Af + (size_t)(mbase + lo) * SS + koff;
            f32x4 a0 = *(const f32x4*)ar;
            f32x4 a1 = *(const f32x4*)(ar + 4);
            #pragma unroll
            for (int j = 0; j < 4; ++j) { af[j] = (short)f2bf(a0[j]); af[4 + j] = (short)f2bf(a1[j]); }
        } else {
            af = *(const short8*)(Ab + (size_t)(mbase + lo) * SS + koff);
        }
        #pragma unroll
        for (int j = 0; j < 4; ++j) {
            int n = nb + j * 16 + lo;
            short8 bf = *(const short8*)(BT + (size_t)n * SS + koff);
            acc[j] = __builtin_amdgcn_mfma_f32_16x16x32_bf16(af, bf, acc[j], 0, 0, 0);
        }
    }

    #pragma unroll
    for (int j = 0; j < 4; ++j) {
        #pragma unroll
        for (int i = 0; i < 4; ++i) {
            int m = mbase + q * 4 + i;
            int n = nb + j * 16 + lo;
            if (MODE == 0) {
                int b = m >> 11, t = m & 2047;
                int gg = n >> 4, cc = n & 15;
                ((unsigned short*)Outp)[((size_t)t * NCH + gg) * 256 + b * 16 + cc] = f2bf(acc[j][i]);
            } else {
                ((float*)Outp)[(size_t)m * SS + n] = acc[j][i];
            }
        }
    }
}

// -------------------- the sequential liquid scan --------------------
// 32 workgroups x 64 threads. WG g owns output columns [g*16, g*16+16).
// U: [t][g][b][c] bf16. AT/KT: [n][k] bf16. hs: [b][t][s] bf16 (exchange + output).
// stats: [t][16][2] fp32 (sum, sumsq). scnt/hcnt: [t] arrival counters.
__global__ __launch_bounds__(64) void scan_kernel(const unsigned short* __restrict__ U,
                                                  const unsigned short* __restrict__ AT,
                                                  const unsigned short* __restrict__ KT,
                                                  const float* __restrict__ ab,
                                                  const float* __restrict__ gn,
                                                  const float* __restrict__ bt,
                                                  unsigned short* __restrict__ hs,
                                                  float* __restrict__ stats,
                                                  int* __restrict__ scnt,
                                                  int* __restrict__ hcnt) {
    __shared__ unsigned short Alds[16][520];
    __shared__ unsigned short Klds[16][520];

    const int g = blockIdx.x;
    const int l = threadIdx.x;
    const int lo = l & 15;   // col-within-chunk for C-layout; batch m for A-frags
    const int q  = l >> 4;

    // stage weight chunk: Alds[c][k] = A[k][g*16+c] (AT is [n][k])
    for (int i = l; i < 16 * 64; i += 64) {
        int cc = i >> 6, seg = i & 63;
        *(short8*)&Alds[cc][seg * 8] = *(const short8*)(AT + ((size_t)(g * 16 + cc)) * SS + seg * 8);
        *(short8*)&Klds[cc][seg * 8] = *(const short8*)(KT + ((size_t)(g * 16 + cc)) * SS + seg * 8);
    }
    __syncthreads();

    const float ab_c = ab[g * 16 + lo];
    const float g_c  = gn[g * 16 + lo];
    const float bt_c = bt[g * 16 + lo];

    float h_own[4] = {0.f, 0.f, 0.f, 0.f};
    float up[4]    = {0.f, 0.f, 0.f, 0.f};

    for (int t = 0; t < TT; ++t) {
        // ---- load this step's u slice (plain; written by prior kernel) ----
        float u4[4];
        #pragma unroll
        for (int i = 0; i < 4; ++i)
            u4[i] = bf2f(U[((size_t)t * NCH + g) * 256 + (q * 4 + i) * 16 + lo]);

        f32x4 accA = {0, 0, 0, 0};
        f32x4 accK = {0, 0, 0, 0};

        if (t > 0) {
            // wait for all 32 WGs to publish h[t-1]
            while (__hip_atomic_load(hcnt + (t - 1), __ATOMIC_RELAXED, SCOPE_AGENT) < NCH) {}
            __builtin_amdgcn_fence(__ATOMIC_ACQUIRE, "agent");
            const unsigned short* hb = hs + ((size_t)lo * TT + (t - 1)) * SS + q * 8;
            #pragma unroll 4
            for (int kk = 0; kk < 16; ++kk) {
                short8 hf  = *(const short8*)(hb + kk * 32);
                short8 afr = *(const short8*)&Alds[lo][kk * 32 + q * 8];
                short8 kfr = *(const short8*)&Klds[lo][kk * 32 + q * 8];
                accA = __builtin_amdgcn_mfma_f32_16x16x32_bf16(hf, afr, accA, 0, 0, 0);
                accK = __builtin_amdgcn_mfma_f32_16x16x32_bf16(hf, kfr, accK, 0, 0, 0);
            }
        }

        // ---- z slice (C-layout: row q*4+i = batch, col lo) ----
        float z[4], s1[4], s2[4];
        #pragma unroll
        for (int i = 0; i < 4; ++i) {
            z[i] = accA[i] + u4[i] + ab_c + accK[i] * up[i];
            s1[i] = z[i];
            s2[i] = z[i] * z[i];
        }

        // ---- per-row partial sums over this chunk's 16 cols (butterfly in low 4 lane bits) ----
        #pragma unroll
        for (int off = 1; off < 16; off <<= 1) {
            #pragma unroll
            for (int i = 0; i < 4; ++i) {
                s1[i] += __shfl_xor(s1[i], off, 64);
                s2[i] += __shfl_xor(s2[i], off, 64);
            }
        }

        // ---- global LN stats ----
        if (lo == 0) {
            #pragma unroll
            for (int i = 0; i < 4; ++i) {
                int r = q * 4 + i;
                __hip_atomic_fetch_add(stats + (size_t)t * 32 + r * 2 + 0, s1[i], __ATOMIC_RELAXED, SCOPE_AGENT);
                __hip_atomic_fetch_add(stats + (size_t)t * 32 + r * 2 + 1, s2[i], __ATOMIC_RELAXED, SCOPE_AGENT);
            }
        }
        __builtin_amdgcn_fence(__ATOMIC_RELEASE, "agent");
        if (l == 0) __hip_atomic_fetch_add(scnt + t, 1, __ATOMIC_RELAXED, SCOPE_AGENT);
        while (__hip_atomic_load(scnt + t, __ATOMIC_RELAXED, SCOPE_AGENT) < NCH) {}
        __builtin_amdgcn_fence(__ATOMIC_ACQUIRE, "agent");

        // ---- LN + exact GELU + state update ----
        #pragma unroll
        for (int i = 0; i < 4; ++i) {
            const float* sp = stats + (size_t)t * 32 + (q * 4 + i) * 2;
            float mu  = sp[0] * (1.0f / SS);
            float var = sp[1] * (1.0f / SS) - mu * mu;
            float rs  = rsqrtf(var + 1e-5f);
            float zn  = (z[i] - mu) * rs * g_c + bt_c;
            float d   = 0.5f * zn * (1.0f + erff(zn * 0.70710678118654752f));
            h_own[i] += d;
            hs[((size_t)(q * 4 + i) * TT + t) * SS + g * 16 + lo] = f2bf(h_own[i]);
            up[i] = u4[i];
        }
        __builtin_amdgcn_fence(__ATOMIC_RELEASE, "agent");
        if (l == 0) __hip_atomic_fetch_add(hcnt + t, 1, __ATOMIC_RELAXED, SCOPE_AGENT);
    }
}

// -------------------- host launch --------------------
extern "C" void kernel_launch(void* const* d_in, const int* in_sizes, int n_in,
                              void* d_out, int out_size, void* d_ws, size_t ws_size,
                              hipStream_t stream) {
    const float* x   = (const float*)d_in[0];
    const float* A0  = (const float*)d_in[1];
    const float* B0  = (const float*)d_in[2];
    const float* C0  = (const float*)d_in[3];
    const float* K0  = (const float*)d_in[4];
    const float* ab0 = (const float*)d_in[5];
    const float* g0  = (const float*)d_in[6];
    const float* bt0 = (const float*)d_in[7];
    const float* A1  = (const float*)d_in[8];
    const float* B1  = (const float*)d_in[9];
    const float* C1  = (const float*)d_in[10];
    const float* K1  = (const float*)d_in[11];
    const float* ab1 = (const float*)d_in[12];
    const float* g1  = (const float*)d_in[13];
    const float* bt1 = (const float*)d_in[14];

    char* ws = (char*)d_ws;
    size_t off = 0;
    auto alloc = [&](size_t bytes) { size_t o = off; off = (off + bytes + 255) & ~(size_t)255; return o; };

    const size_t U_BYTES  = (size_t)TT * NCH * 256 * 2;      // 33.5 MB bf16
    const size_t HS_BYTES = (size_t)NB * TT * SS * 2;        // 33.5 MB bf16
    const size_t WT_BYTES = (size_t)SS * SS * 2;             // 512 KB bf16

    unsigned short* U0  = (unsigned short*)(ws + alloc(U_BYTES));
    unsigned short* U1  = (unsigned short*)(ws + alloc(U_BYTES));
    unsigned short* hs0 = (unsigned short*)(ws + alloc(HS_BYTES));
    unsigned short* hs1 = (unsigned short*)(ws + alloc(HS_BYTES));
    unsigned short* AT0 = (unsigned short*)(ws + alloc(WT_BYTES));
    unsigned short* KT0 = (unsigned short*)(ws + alloc(WT_BYTES));
    unsigned short* AT1 = (unsigned short*)(ws + alloc(WT_BYTES));
    unsigned short* KT1 = (unsigned short*)(ws + alloc(WT_BYTES));
    unsigned short* B0T = (unsigned short*)(ws + alloc(WT_BYTES));
    unsigned short* WT  = (unsigned short*)(ws + alloc(WT_BYTES));
    unsigned short* C1T = (unsigned short*)(ws + alloc(WT_BYTES));
    float*          Wf  = (float*)(ws + alloc((size_t)SS * SS * 4));
    // contiguous zero region: stats0, stats1, scnt0, hcnt0, scnt1, hcnt1
    char* zbase = ws + alloc((size_t)(TT * 32 * 4) * 2 + (size_t)(TT * 4) * 4);
    float* stats0 = (float*)zbase;
    float* stats1 = (float*)(zbase + (size_t)TT * 32 * 4);
    int*   scnt0  = (int*)(zbase + (size_t)TT * 32 * 4 * 2);
    int*   hcnt0  = scnt0 + TT;
    int*   scnt1  = hcnt0 + TT;
    int*   hcnt1  = scnt1 + TT;

    // 1) zero flags + stats
    int nz = (TT * 32 * 2) + (TT * 4);
    zero_kernel<<<128, 256, 0, stream>>>((unsigned int*)zbase, nz);

    // 2) weight transposes/converts
    tcvt_kernel<<<256, 256, 0, stream>>>(A0, AT0);
    tcvt_kernel<<<256, 256, 0, stream>>>(K0, KT0);
    tcvt_kernel<<<256, 256, 0, stream>>>(A1, AT1);
    tcvt_kernel<<<256, 256, 0, stream>>>(K1, KT1);
    tcvt_kernel<<<256, 256, 0, stream>>>(B0, B0T);
    tcvt_kernel<<<256, 256, 0, stream>>>(C1, C1T);

    // 3) W = C0 @ B1, then transpose
    wmm_kernel<<<512, 256, 0, stream>>>(C0, B1, Wf);
    tcvt_kernel<<<256, 256, 0, stream>>>(Wf, WT);

    // 4) U0 = x @ B0   (fp32 A path, scan layout out)
    gemm_kernel<true, 0><<<4096, 256, 0, stream>>>((const void*)x, B0T, (void*)U0);

    // 5) layer-0 scan
    scan_kernel<<<NCH, 64, 0, stream>>>(U0, AT0, KT0, ab0, g0, bt0, hs0, stats0, scnt0, hcnt0);

    // 6) U1 = hs0 @ (C0@B1)
    gemm_kernel<false, 0><<<4096, 256, 0, stream>>>((const void*)hs0, WT, (void*)U1);

    // 7) layer-1 scan
    scan_kernel<<<NCH, 64, 0, stream>>>(U1, AT1, KT1, ab1, g1, bt1, hs1, stats1, scnt1, hcnt1);

    // 8) out = hs1 @ C1
    gemm_kernel<false, 1><<<4096, 256, 0, stream>>>((const void*)hs1, C1T, d_out);
}

// Round 3
// 41572.131 us; speedup vs baseline: 1.1057x; 1.1057x over previous
//
#include <hip/hip_runtime.h>

using half8  = __attribute__((ext_vector_type(8))) _Float16;
using half2v = __attribute__((ext_vector_type(2))) _Float16;
using f32x4  = __attribute__((ext_vector_type(4))) float;

static constexpr int TT = 2048;   // time steps
static constexpr int NB = 16;     // batch
static constexpr int SS = 512;    // state dim

// ---- f16 dot helper: v_dot2_f32_f16 if available ----
__device__ __forceinline__ float dot8(half8 w, half8 h, float acc) {
    union H8 { half8 v; half2v p[4]; };
    H8 W; W.v = w; H8 Hh; Hh.v = h;
#if __has_builtin(__builtin_amdgcn_fdot2)
    #pragma unroll
    for (int j = 0; j < 4; ++j) acc = __builtin_amdgcn_fdot2(W.p[j], Hh.p[j], acc, false);
#else
    #pragma unroll
    for (int j = 0; j < 4; ++j)
        acc += (float)W.p[j][0] * (float)Hh.p[j][0] + (float)W.p[j][1] * (float)Hh.p[j][1];
#endif
    return acc;
}

// -------------------- transpose + fp32->f16 (512x512): out[c][r] = in[r][c] --------------------
__global__ __launch_bounds__(256) void tcvt_kernel(const float* __restrict__ in,
                                                   _Float16* __restrict__ out) {
    __shared__ float tile[32][33];
    int bid = blockIdx.x;
    int rb = (bid >> 4) * 32, cb = (bid & 15) * 32;
    int tx = threadIdx.x & 31, ty = threadIdx.x >> 5;
    for (int rr = ty; rr < 32; rr += 8)
        tile[rr][tx] = in[(size_t)(rb + rr) * SS + cb + tx];
    __syncthreads();
    for (int rr = ty; rr < 32; rr += 8)
        out[(size_t)(cb + rr) * SS + rb + tx] = (_Float16)tile[tx][rr];
}

// -------------------- pack weights for scan: W[kk][c][8] f16 from fp32 [k][c] --------------------
__global__ __launch_bounds__(256) void wpack_kernel(const float* __restrict__ in,
                                                    _Float16* __restrict__ out) {
    int idx = blockIdx.x * blockDim.x + threadIdx.x;   // 64*512 = 32768
    int kk = idx >> 9, c = idx & 511;
    half8 v;
    #pragma unroll
    for (int j = 0; j < 8; ++j) v[j] = (_Float16)in[(size_t)(kk * 8 + j) * SS + c];
    *(half8*)(out + (size_t)idx * 8) = v;
}

// -------------------- W = C0 @ B1 (512x512x512 fp32) --------------------
__global__ __launch_bounds__(256) void wmm_kernel(const float* __restrict__ C0,
                                                  const float* __restrict__ B1,
                                                  float* __restrict__ W) {
    int k = blockIdx.x;
    int tid = threadIdx.x;
    const float* crow = C0 + (size_t)k * SS;
    float s0 = 0.f, s1 = 0.f;
    for (int m = 0; m < SS; ++m) {
        float cv = crow[m];
        s0 += cv * B1[(size_t)m * SS + tid];
        s1 += cv * B1[(size_t)m * SS + tid + 256];
    }
    W[(size_t)k * SS + tid] = s0;
    W[(size_t)k * SS + tid + 256] = s1;
}

// -------------------- big GEMM: M=32768(b*2048+t), N=512, K=512 --------------------
// BT: f16 [n][k]. ALAY 0: A fp32 [m][k]; ALAY 1: A f16 [m][k].
// MODE 0: f16 out[m][n]; MODE 1: fp32 out[m][n].
template <int ALAY, int MODE>
__global__ __launch_bounds__(256) void gemm_kernel(const void* __restrict__ Aptr,
                                                   const _Float16* __restrict__ BT,
                                                   void* __restrict__ Outp) {
    int lane = threadIdx.x & 63;
    int wv   = threadIdx.x >> 6;
    int wid  = blockIdx.x * 4 + wv;
    int mt   = wid >> 3;
    int nb   = (wid & 7) * 64;
    int mbase = mt * 16;
    int lo = lane & 15, q = lane >> 4;

    f32x4 acc[4] = {{0,0,0,0},{0,0,0,0},{0,0,0,0},{0,0,0,0}};

    const float*    Af = (const float*)Aptr;
    const _Float16* Ah = (const _Float16*)Aptr;
    size_t arow = (size_t)(mbase + lo) * SS;

    #pragma unroll 2
    for (int kk = 0; kk < 16; ++kk) {
        int koff = kk * 32 + q * 8;
        half8 af;
        if (ALAY == 0) {
            const float* ar = Af + arow + koff;
            f32x4 a0 = *(const f32x4*)ar;
            f32x4 a1 = *(const f32x4*)(ar + 4);
            #pragma unroll
            for (int j = 0; j < 4; ++j) { af[j] = (_Float16)a0[j]; af[4 + j] = (_Float16)a1[j]; }
        } else {
            af = *(const half8*)(Ah + arow + koff);
        }
        #pragma unroll
        for (int j = 0; j < 4; ++j) {
            int n = nb + j * 16 + lo;
            half8 bf = *(const half8*)(BT + (size_t)n * SS + koff);
            acc[j] = __builtin_amdgcn_mfma_f32_16x16x32_f16(af, bf, acc[j], 0, 0, 0);
        }
    }

    #pragma unroll
    for (int j = 0; j < 4; ++j) {
        #pragma unroll
        for (int i = 0; i < 4; ++i) {
            int m = mbase + q * 4 + i;
            int n = nb + j * 16 + lo;
            if (MODE == 0) ((_Float16*)Outp)[(size_t)m * SS + n] = (_Float16)acc[j][i];
            else           ((float*)Outp)[(size_t)m * SS + n] = acc[j][i];
        }
    }
}

// -------------------- per-batch liquid scan: ZERO inter-WG communication --------------------
// Grid = 16 WGs (one per batch row), 256 threads, 2 cols/thread.
// U:  f16 [b][t][c]  (this WG reads batch b's rows)
// WA/WK: f16 [kk][c][8]  (packed; streamed from L2 every step, ~1MB/step)
// hs: f16 [b][t][c]  (full history out -> feeds next GEMM)
__global__ __launch_bounds__(256) void scan_kernel(const _Float16* __restrict__ U,
                                                   const _Float16* __restrict__ WA,
                                                   const _Float16* __restrict__ WK,
                                                   const float* __restrict__ ab,
                                                   const float* __restrict__ gn,
                                                   const float* __restrict__ bt,
                                                   _Float16* __restrict__ hs) {
    __shared__ _Float16 h16[SS];
    __shared__ float red[8];          // 4 waves x (s1, s2)

    const int b    = blockIdx.x;
    const int tid  = threadIdx.x;     // 0..255
    const int c0   = tid * 2;
    const int lane = tid & 63;
    const int wv   = tid >> 6;

    const _Float16* Ub = U  + (size_t)b * TT * SS;
    _Float16*       hb = hs + (size_t)b * TT * SS;

    // zero h
    *(half2v*)(h16 + c0) = half2v{(_Float16)0.f, (_Float16)0.f};
    float hm0 = 0.f, hm1 = 0.f;
    float up0 = 0.f, up1 = 0.f;
    const float abc0 = ab[c0], abc1 = ab[c0 + 1];
    const float gc0  = gn[c0], gc1  = gn[c0 + 1];
    const float btc0 = bt[c0], btc1 = bt[c0 + 1];
    __syncthreads();

    for (int t = 0; t < TT; ++t) {
        // u for this step (off critical path: issue early)
        half2v uh = *(const half2v*)(Ub + (size_t)t * SS + c0);
        float u0 = (float)uh[0], u1 = (float)uh[1];

        float dA0 = 0.f, dA1 = 0.f, dK0 = 0.f, dK1 = 0.f;
        if (t > 0) {
            #pragma unroll 4
            for (int kk = 0; kk < 64; ++kk) {
                half8 hc = *(const half8*)(h16 + kk * 8);   // LDS broadcast (same addr all lanes)
                const half8* wa = (const half8*)(WA + ((size_t)kk * SS + c0) * 8);
                const half8* wk = (const half8*)(WK + ((size_t)kk * SS + c0) * 8);
                half8 wa0 = wa[0], wa1 = wa[1];
                half8 wk0 = wk[0], wk1 = wk[1];
                dA0 = dot8(wa0, hc, dA0);
                dA1 = dot8(wa1, hc, dA1);
                dK0 = dot8(wk0, hc, dK0);
                dK1 = dot8(wk1, hc, dK1);
            }
        }

        float z0 = dA0 + u0 + abc0 + dK0 * up0;
        float z1 = dA1 + u1 + abc1 + dK1 * up1;
        up0 = u0; up1 = u1;

        // LN stats: wave butterfly then 8-float LDS exchange
        float p1 = z0 + z1;
        float p2 = z0 * z0 + z1 * z1;
        #pragma unroll
        for (int off = 1; off < 64; off <<= 1) {
            p1 += __shfl_xor(p1, off, 64);
            p2 += __shfl_xor(p2, off, 64);
        }
        if (lane == 0) { red[wv * 2] = p1; red[wv * 2 + 1] = p2; }
        __syncthreads();
        float S1 = red[0] + red[2] + red[4] + red[6];
        float S2 = red[1] + red[3] + red[5] + red[7];
        float mu  = S1 * (1.0f / SS);
        float var = S2 * (1.0f / SS) - mu * mu;
        float rs  = rsqrtf(var + 1e-5f);

        float zn0 = (z0 - mu) * rs * gc0 + btc0;
        float zn1 = (z1 - mu) * rs * gc1 + btc1;
        hm0 += 0.5f * zn0 * (1.0f + erff(zn0 * 0.70710678118654752f));
        hm1 += 0.5f * zn1 * (1.0f + erff(zn1 * 0.70710678118654752f));

        half2v hw; hw[0] = (_Float16)hm0; hw[1] = (_Float16)hm1;
        *(half2v*)(h16 + c0) = hw;                       // safe: all reads of h16 done pre-barrier
        *(half2v*)(hb + (size_t)t * SS + c0) = hw;       // history out (fire & forget)
        __syncthreads();                                  // h16/red ready for next step
    }
}

// -------------------- host launch --------------------
extern "C" void kernel_launch(void* const* d_in, const int* in_sizes, int n_in,
                              void* d_out, int out_size, void* d_ws, size_t ws_size,
                              hipStream_t stream) {
    const float* x   = (const float*)d_in[0];
    const float* A0  = (const float*)d_in[1];
    const float* B0  = (const float*)d_in[2];
    const float* C0  = (const float*)d_in[3];
    const float* K0  = (const float*)d_in[4];
    const float* ab0 = (const float*)d_in[5];
    const float* g0  = (const float*)d_in[6];
    const float* bt0 = (const float*)d_in[7];
    const float* A1  = (const float*)d_in[8];
    const float* B1  = (const float*)d_in[9];
    const float* C1  = (const float*)d_in[10];
    const float* K1  = (const float*)d_in[11];
    const float* ab1 = (const float*)d_in[12];
    const float* g1  = (const float*)d_in[13];
    const float* bt1 = (const float*)d_in[14];

    char* ws = (char*)d_ws;
    size_t off = 0;
    auto alloc = [&](size_t bytes) { size_t o = off; off = (off + bytes + 255) & ~(size_t)255; return o; };

    const size_t BUF_BYTES = (size_t)NB * TT * SS * 2;   // 33.5 MB f16
    const size_t WP_BYTES  = (size_t)SS * SS * 2;        // 512 KB f16

    _Float16* U0  = (_Float16*)(ws + alloc(BUF_BYTES));
    _Float16* U1  = (_Float16*)(ws + alloc(BUF_BYTES));
    _Float16* hs0 = (_Float16*)(ws + alloc(BUF_BYTES));
    _Float16* hs1 = (_Float16*)(ws + alloc(BUF_BYTES));
    _Float16* WA0 = (_Float16*)(ws + alloc(WP_BYTES));
    _Float16* WK0 = (_Float16*)(ws + alloc(WP_BYTES));
    _Float16* WA1 = (_Float16*)(ws + alloc(WP_BYTES));
    _Float16* WK1 = (_Float16*)(ws + alloc(WP_BYTES));
    _Float16* B0T = (_Float16*)(ws + alloc(WP_BYTES));
    _Float16* WT  = (_Float16*)(ws + alloc(WP_BYTES));
    _Float16* C1T = (_Float16*)(ws + alloc(WP_BYTES));
    float*    Wf  = (float*)(ws + alloc((size_t)SS * SS * 4));

    // weight preps
    wpack_kernel<<<128, 256, 0, stream>>>(A0, WA0);
    wpack_kernel<<<128, 256, 0, stream>>>(K0, WK0);
    wpack_kernel<<<128, 256, 0, stream>>>(A1, WA1);
    wpack_kernel<<<128, 256, 0, stream>>>(K1, WK1);
    tcvt_kernel<<<256, 256, 0, stream>>>(B0, B0T);
    tcvt_kernel<<<256, 256, 0, stream>>>(C1, C1T);
    wmm_kernel<<<512, 256, 0, stream>>>(C0, B1, Wf);     // W = C0 @ B1 (layer-fold)
    tcvt_kernel<<<256, 256, 0, stream>>>(Wf, WT);

    // U0 = x @ B0
    gemm_kernel<0, 0><<<4096, 256, 0, stream>>>((const void*)x, B0T, (void*)U0);

    // layer-0 scan (per-batch, no inter-WG sync)
    scan_kernel<<<NB, 256, 0, stream>>>(U0, WA0, WK0, ab0, g0, bt0, hs0);

    // U1 = hs0 @ (C0@B1)
    gemm_kernel<1, 0><<<4096, 256, 0, stream>>>((const void*)hs0, WT, (void*)U1);

    // layer-1 scan
    scan_kernel<<<NB, 256, 0, stream>>>(U1, WA1, WK1, ab1, g1, bt1, hs1);

    // out = hs1 @ C1
    gemm_kernel<1, 1><<<4096, 256, 0, stream>>>((const void*)hs1, C1T, d_out);
}